// Round 3
// baseline (132.716 us; speedup 1.0000x reference)
//
#include <hip/hip_runtime.h>

// SoftProjection: B=4, N=8192 pts, M=4096 queries, F=64 feat, K=16 NN.
// R3: 1024 blocks x 256 thr (QPB=16) -> 4 blocks/CU (4 independent barrier
// groups); register-staged double-buffered LDS chunks (1 barrier/chunk);
// packed-fp32 scan (v_pk_fma_f32 via __builtin_elementwise_fma on float2).
// Selection metric val = |p|^2 - 2 q.p (order == d2 order per query), staged
// ps in LDS. Threshold t = max over the 2 point-halves of the 8th-smallest
// per-lane minimum (radix/ballot select) -- provable upper bound on the true
// 16th NN. Pass B collects survivors val<=t (E~20, cap 52), exact rank by
// (val,idx). Epilogue recomputes exact direct-form d2 for softmax.

#define BB 4
#define NN 8192
#define MM 4096
#define FF 64
#define KK 16
#define CHUNK 1024
#define NCHUNK 8
#define QPW 8
#define QPB 16
#define SCAP 52
#define NTHR 256
#define WAVES 4

typedef float f32x2 __attribute__((ext_vector_type(2)));

__device__ __forceinline__ f32x2 pkfma(f32x2 a, f32x2 b, f32x2 c) {
#if __has_builtin(__builtin_elementwise_fma)
    return __builtin_elementwise_fma(a, b, c);
#else
    f32x2 r;
    r.x = fmaf(a.x, b.x, c.x);
    r.y = fmaf(a.y, b.y, c.y);
    return r;
#endif
}

__global__ __launch_bounds__(256) void transpose_feat(const float* __restrict__ pf,
                                                      float* __restrict__ pfT) {
    __shared__ float tile[64][65];
    const int b = blockIdx.y;
    const int n0 = blockIdx.x * 64;
    const int t = threadIdx.x;
    const int nq = t & 15;  // float4 column: n = nq*4
    const int r0 = t >> 4;  // 0..15
#pragma unroll
    for (int i = 0; i < 4; ++i) {
        int f = r0 + i * 16;
        float4 v = *(const float4*)(pf + (size_t)b * FF * NN + (size_t)f * NN +
                                    n0 + nq * 4);
        tile[f][nq * 4 + 0] = v.x;
        tile[f][nq * 4 + 1] = v.y;
        tile[f][nq * 4 + 2] = v.z;
        tile[f][nq * 4 + 3] = v.w;
    }
    __syncthreads();
    const int f4 = (t & 15) * 4;
    const int nr = t >> 4;
#pragma unroll
    for (int i = 0; i < 4; ++i) {
        int n = nr + i * 16;
        float4 v;
        v.x = tile[f4 + 0][n];
        v.y = tile[f4 + 1][n];
        v.z = tile[f4 + 2][n];
        v.w = tile[f4 + 3][n];
        *(float4*)(pfT + (size_t)b * NN * FF + (size_t)(n0 + n) * FF + f4) = v;
    }
}

__device__ __forceinline__ unsigned mapf(float f) {
    unsigned u = __float_as_uint(f);
    return (u & 0x80000000u) ? ~u : (u | 0x80000000u);
}
__device__ __forceinline__ float unmapf(unsigned k) {
    return (k & 0x80000000u) ? __uint_as_float(k ^ 0x80000000u)
                             : __uint_as_float(~k);
}

// load chunk C into registers (no wait here; compiler inserts waitcnt at use)
#define LOADREG(C)                                   \
    do {                                             \
        int base_ = (C)*CHUNK + t * 4;               \
        rx = *(const float4*)(pcb + base_);          \
        ry = *(const float4*)(pcb + NN + base_);     \
        rz = *(const float4*)(pcb + 2 * NN + base_); \
    } while (0)

// write registers into LDS buffer P (x, y, z, ps)
#define WRITELDS(P)                                                   \
    do {                                                              \
        int i_ = t * 4;                                               \
        float4 p4_;                                                   \
        p4_.x = fmaf(rx.x, rx.x, fmaf(ry.x, ry.x, rz.x * rz.x));      \
        p4_.y = fmaf(rx.y, rx.y, fmaf(ry.y, ry.y, rz.y * rz.y));      \
        p4_.z = fmaf(rx.z, rx.z, fmaf(ry.z, ry.z, rz.z * rz.z));      \
        p4_.w = fmaf(rx.w, rx.w, fmaf(ry.w, ry.w, rz.w * rz.w));      \
        *(float4*)(&s_pts[P][0][i_]) = rx;                            \
        *(float4*)(&s_pts[P][1][i_]) = ry;                            \
        *(float4*)(&s_pts[P][2][i_]) = rz;                            \
        *(float4*)(&s_pts[P][3][i_]) = p4_;                           \
    } while (0)

#define PUSH(WQ, V, I)                                              \
    do {                                                            \
        int pos_ = atomicAdd(&s_cnt[WQ], 1);                        \
        if (pos_ < SCAP) {                                          \
            s_surv[((WQ)*SCAP + pos_) * 2] = (V);                   \
            s_surv[((WQ)*SCAP + pos_) * 2 + 1] = __int_as_float(I); \
        }                                                           \
    } while (0)

__global__ __launch_bounds__(NTHR, 4) void soft_proj_kernel(
    const float* __restrict__ pc, const float* __restrict__ qc,
    const float* __restrict__ pf, const float* __restrict__ pfT,
    const float* __restrict__ temp, float* __restrict__ out, int useT) {
    __shared__ __align__(16) float s_pts[2][4][CHUNK];      // 32768 B
    __shared__ __align__(16) float s_surv[QPB * SCAP * 2];  // 6656 B
    __shared__ int s_cnt[QPB];                              // 64 B
    __shared__ int s_sel[QPB * KK];                         // 1024 B
    __shared__ float s_thr[2 * QPB];                        // 128 B => ~40.6 KB

    const int bid = blockIdx.x;
    const int b = bid >> 8;             // 256 blocks per batch
    const int m0 = (bid & 255) * QPB;   // 16 queries per block
    const int t = threadIdx.x;
    const int wave = t >> 6;
    const int lane = t & 63;
    const int pairIdx = wave & 1;  // which 8-query group
    const int half = wave >> 1;    // which point half

    const float* pcb = pc + (size_t)b * 3 * NN;
    const float* qcb = qc + (size_t)b * 3 * MM;

    // scan-phase query constants: -2*q, broadcast to f32x2
    f32x2 qx2[QPW], qy2[QPW], qz2[QPW];
#pragma unroll
    for (int q = 0; q < QPW; ++q) {
        int m = m0 + pairIdx * QPW + q;
        float vx = -2.0f * qcb[m];
        float vy = -2.0f * qcb[MM + m];
        float vz = -2.0f * qcb[2 * MM + m];
        qx2[q].x = vx; qx2[q].y = vx;
        qy2[q].x = vy; qy2[q].y = vy;
        qz2[q].x = vz; qz2[q].y = vz;
    }

    float4 rx, ry, rz;
    float mn[QPW];
#pragma unroll
    for (int q = 0; q < QPW; ++q) mn[q] = 3.0e38f;

    // ---------------- pass A: per-lane min of val -------------------------
    LOADREG(0);
    WRITELDS(0);
    __syncthreads();
    for (int c = 0; c < NCHUNK; ++c) {
        const int p = c & 1;
        if (c + 1 < NCHUNK) LOADREG(c + 1);
        const int ob = half * 512 + lane * 4;
#pragma unroll
        for (int g = 0; g < 2; ++g) {
            int oo = ob + g * 256;
            float4 x4 = *(const float4*)(&s_pts[p][0][oo]);
            float4 y4 = *(const float4*)(&s_pts[p][1][oo]);
            float4 z4 = *(const float4*)(&s_pts[p][2][oo]);
            float4 p4 = *(const float4*)(&s_pts[p][3][oo]);
            f32x2 x01 = {x4.x, x4.y}, x23 = {x4.z, x4.w};
            f32x2 y01 = {y4.x, y4.y}, y23 = {y4.z, y4.w};
            f32x2 z01 = {z4.x, z4.y}, z23 = {z4.z, z4.w};
            f32x2 s01 = {p4.x, p4.y}, s23 = {p4.z, p4.w};
#pragma unroll
            for (int q = 0; q < QPW; ++q) {
                f32x2 v01 = pkfma(x01, qx2[q], pkfma(y01, qy2[q], pkfma(z01, qz2[q], s01)));
                f32x2 v23 = pkfma(x23, qx2[q], pkfma(y23, qy2[q], pkfma(z23, qz2[q], s23)));
                mn[q] = fminf(mn[q],
                              fminf(fminf(v01.x, v01.y), fminf(v23.x, v23.y)));
            }
        }
        if (c + 1 < NCHUNK) WRITELDS(p ^ 1);
        __syncthreads();
    }

    // ---- per-wave radix select: 8th-smallest of 64 lane minima ------------
    float thrv[QPW];
#pragma unroll
    for (int q = 0; q < QPW; ++q) {
        unsigned key = mapf(mn[q]);
        unsigned res = 0u;
        for (int bb = 31; bb >= 8; --bb) {
            unsigned cand = res | (1u << bb);
            unsigned long long bal = __ballot(key < cand);
            int c2 = __popcll(bal);
            if (c2 < 8) res = cand;
        }
        thrv[q] = unmapf(res | 0xFFu);  // upper bound on 8th-smallest lane min
    }
    if (lane == 0) {
#pragma unroll
        for (int q = 0; q < QPW; ++q)
            s_thr[half * QPB + pairIdx * QPW + q] = thrv[q];
    }
    if (t < QPB) s_cnt[t] = 0;
    __syncthreads();
    // t = max(tA8, tB8): >=8 points <= t in each half => >=16 total.
#pragma unroll
    for (int q = 0; q < QPW; ++q)
        thrv[q] = fmaxf(s_thr[pairIdx * QPW + q], s_thr[QPB + pairIdx * QPW + q]);

    // ---------------- pass B: collect survivors val <= t -------------------
    LOADREG(0);
    WRITELDS(0);
    __syncthreads();
    for (int c = 0; c < NCHUNK; ++c) {
        const int p = c & 1;
        if (c + 1 < NCHUNK) LOADREG(c + 1);
        const int ob = half * 512 + lane * 4;
#pragma unroll
        for (int g = 0; g < 2; ++g) {
            int oo = ob + g * 256;
            float4 x4 = *(const float4*)(&s_pts[p][0][oo]);
            float4 y4 = *(const float4*)(&s_pts[p][1][oo]);
            float4 z4 = *(const float4*)(&s_pts[p][2][oo]);
            float4 p4 = *(const float4*)(&s_pts[p][3][oo]);
            f32x2 x01 = {x4.x, x4.y}, x23 = {x4.z, x4.w};
            f32x2 y01 = {y4.x, y4.y}, y23 = {y4.z, y4.w};
            f32x2 z01 = {z4.x, z4.y}, z23 = {z4.z, z4.w};
            f32x2 s01 = {p4.x, p4.y}, s23 = {p4.z, p4.w};
            int gi = c * CHUNK + oo;
#pragma unroll
            for (int q = 0; q < QPW; ++q) {
                int wqq = pairIdx * QPW + q;
                f32x2 v01 = pkfma(x01, qx2[q], pkfma(y01, qy2[q], pkfma(z01, qz2[q], s01)));
                f32x2 v23 = pkfma(x23, qx2[q], pkfma(y23, qy2[q], pkfma(z23, qz2[q], s23)));
                if (v01.x <= thrv[q]) PUSH(wqq, v01.x, gi + 0);
                if (v01.y <= thrv[q]) PUSH(wqq, v01.y, gi + 1);
                if (v23.x <= thrv[q]) PUSH(wqq, v23.x, gi + 2);
                if (v23.y <= thrv[q]) PUSH(wqq, v23.y, gi + 3);
            }
        }
        if (c + 1 < NCHUNK) WRITELDS(p ^ 1);
        __syncthreads();
    }
    __syncthreads();

    // ------------- exact select: rank survivors by (val, idx) --------------
#pragma unroll
    for (int qq = 0; qq < 4; ++qq) {
        int wq = wave * 4 + qq;
        int cnt = __builtin_amdgcn_readfirstlane(s_cnt[wq]);
        if (cnt > SCAP) cnt = SCAP;
        bool valid = lane < cnt;
        float mv = 0.f;
        int mi = 0;
        if (valid) {
            mv = s_surv[(wq * SCAP + lane) * 2];
            mi = __float_as_int(s_surv[(wq * SCAP + lane) * 2 + 1]);
        }
        int rank = 0;
        for (int j = 0; j < cnt; ++j) {
            float vj = s_surv[(wq * SCAP + j) * 2];
            int ij = __float_as_int(s_surv[(wq * SCAP + j) * 2 + 1]);
            if (valid && (vj < mv || (vj == mv && ij < mi))) rank++;
        }
        if (valid && rank < KK) s_sel[wq * KK + rank] = mi;
    }
    __syncthreads();  // survivors dead; s_surv becomes output stage

    // ---------------- softmax + gather + accumulate ------------------------
    float* stage = s_surv;  // [67 rows][17 cols]
    float tval = temp[0];
    float sigma = fmaxf(tval * tval, 1.0e-4f);
    float inv_sigma = 1.0f / sigma;
    const float* pfTb = pfT + (size_t)b * NN * FF;
    const float* pfb = pf + (size_t)b * FF * NN;

#pragma unroll
    for (int qq = 0; qq < 4; ++qq) {
        int wq = wave * 4 + qq;
        int m = m0 + wq;
        float qxe = qcb[m], qye = qcb[MM + m], qze = qcb[2 * MM + m];
        int ik[KK];
        float dk[KK];
#pragma unroll
        for (int k = 0; k < KK; ++k) {
            int ii = __builtin_amdgcn_readfirstlane(s_sel[wq * KK + k]);
            ik[k] = ii;
            float px = pcb[ii], py = pcb[NN + ii], pz = pcb[2 * NN + ii];
            float dx = px - qxe, dy = py - qye, dz = pz - qze;
            dk[k] = fmaf(dx, dx, fmaf(dy, dy, dz * dz));  // exact direct form
        }
        float dmin = dk[0];
#pragma unroll
        for (int k = 1; k < KK; ++k) dmin = fminf(dmin, dk[k]);
        float ssum = 0.f, facc = 0.f, sx = 0.f, sy = 0.f, sz = 0.f;
#pragma unroll
        for (int k = 0; k < KK; ++k) {
            float e = __expf((dmin - dk[k]) * inv_sigma);
            ssum += e;
            float px = pcb[ik[k]], py = pcb[NN + ik[k]], pz = pcb[2 * NN + ik[k]];
            sx = fmaf(e, px, sx);
            sy = fmaf(e, py, sy);
            sz = fmaf(e, pz, sz);
            float fv = useT ? pfTb[(size_t)ik[k] * FF + lane]
                            : pfb[(size_t)lane * NN + ik[k]];
            facc = fmaf(e, fv, facc);
        }
        float rs = 1.0f / ssum;
        stage[lane * 17 + wq] = facc * rs;
        if (lane == 0) {
            stage[64 * 17 + wq] = sx * rs;
            stage[65 * 17 + wq] = sy * rs;
            stage[66 * 17 + wq] = sz * rs;
        }
    }
    __syncthreads();

    // ---------------- coalesced write-out ----------------------------------
    const size_t featOff = (size_t)BB * 3 * MM;
    for (int j = t; j < 67 * QPB; j += NTHR) {
        int row = j >> 4, col = j & 15;
        float v = stage[row * 17 + col];
        int m = m0 + col;
        if (row < 64)
            out[featOff + (size_t)b * FF * MM + (size_t)row * MM + m] = v;
        else
            out[(size_t)b * 3 * MM + (size_t)(row - 64) * MM + m] = v;
    }
}

extern "C" void kernel_launch(void* const* d_in, const int* in_sizes, int n_in,
                              void* d_out, int out_size, void* d_ws, size_t ws_size,
                              hipStream_t stream) {
    (void)in_sizes; (void)n_in; (void)out_size;
    const float* pc = (const float*)d_in[0];
    const float* qc = (const float*)d_in[1];
    const float* pf = (const float*)d_in[2];
    const float* temp = (const float*)d_in[3];
    float* out = (float*)d_out;
    float* pfT = (float*)d_ws;
    const size_t needT = (size_t)BB * NN * FF * sizeof(float);  // 8 MB
    int useT = (ws_size >= needT && d_ws != nullptr) ? 1 : 0;

    if (useT) {
        hipLaunchKernelGGL(transpose_feat, dim3(NN / 64, BB), dim3(256), 0, stream,
                           pf, pfT);
    }
    hipLaunchKernelGGL(soft_proj_kernel, dim3((BB * MM) / QPB), dim3(NTHR), 0,
                       stream, pc, qc, pf, pfT, temp, out, useT);
}